// Round 1
// baseline (4307.789 us; speedup 1.0000x reference)
//
#include <hip/hip_runtime.h>
#include <math.h>

#define DMODEL 512
#define T_SEQ 2048
#define NH 8
#define DH 64
// rows of the flattened (B*T, D) activations
#define M_ROWS 4096

// ---------------------------------------------------------------------------
// Generic C = A(M x 512) @ W(512 x 512) fp32 GEMM, 64x64 tile, BK=16.
// blockIdx.z selects one of four weight matrices / output slabs (for the
// fused QKVG projection); for a single GEMM launch with gridDim.z == 1.
// ---------------------------------------------------------------------------
__global__ __launch_bounds__(256) void gemm512_k(
    const float* __restrict__ A,
    const float* __restrict__ W0, const float* __restrict__ W1,
    const float* __restrict__ W2, const float* __restrict__ W3,
    float* __restrict__ C, long coutStride)
{
  __shared__ float As[16][64];   // As[kk][m] (A tile transposed)
  __shared__ float Bs[16][64];   // Bs[kk][n]
  const int z = blockIdx.z;
  const float* W = (z == 0) ? W0 : (z == 1) ? W1 : (z == 2) ? W2 : W3;
  float* Cz = C + (long)z * coutStride;
  const int n0 = blockIdx.x * 64, m0 = blockIdx.y * 64;
  const int tid = threadIdx.x, tx = tid & 15, ty = tid >> 4;
  const int ai = tid >> 2, akq = tid & 3;     // A loader: row, float4-in-row
  const int bkk = tid >> 4, bnq = tid & 15;   // B loader: k-row, float4-in-row
  float acc[4][4] = {{0.0f}};
  for (int k0 = 0; k0 < 512; k0 += 16) {
    float4 av = *(const float4*)&A[(size_t)(m0 + ai) * DMODEL + k0 + akq * 4];
    float4 bv = *(const float4*)&W[(size_t)(k0 + bkk) * DMODEL + n0 + bnq * 4];
    As[akq*4+0][ai] = av.x; As[akq*4+1][ai] = av.y;
    As[akq*4+2][ai] = av.z; As[akq*4+3][ai] = av.w;
    *(float4*)&Bs[bkk][bnq*4] = bv;
    __syncthreads();
    #pragma unroll
    for (int kk = 0; kk < 16; ++kk) {
      float4 a = *(const float4*)&As[kk][ty*4];
      float4 b = *(const float4*)&Bs[kk][tx*4];
      float avv[4] = {a.x, a.y, a.z, a.w};
      float bvv[4] = {b.x, b.y, b.z, b.w};
      #pragma unroll
      for (int ii = 0; ii < 4; ++ii)
        #pragma unroll
        for (int jj = 0; jj < 4; ++jj)
          acc[ii][jj] = fmaf(avv[ii], bvv[jj], acc[ii][jj]);
    }
    __syncthreads();
  }
  #pragma unroll
  for (int ii = 0; ii < 4; ++ii) {
    float4 o = make_float4(acc[ii][0], acc[ii][1], acc[ii][2], acc[ii][3]);
    *(float4*)&Cz[(size_t)(m0 + ty*4 + ii) * DMODEL + n0 + tx*4] = o;
  }
}

// ---------------------------------------------------------------------------
// Flash-style retention. One block per (b, h, 64-row Q tile). Iterates over
// K/V tiles m-tile <= q-tile, applies decay gamma^(t-m)/sqrt(dh) with causal
// mask, accumulates O += (S*decay) @ V without materializing full scores.
// ---------------------------------------------------------------------------
__global__ __launch_bounds__(256) void retention_k(
    const float* __restrict__ Qg, const float* __restrict__ Kg,
    const float* __restrict__ Vg, float* __restrict__ RET)
{
  __shared__ float Qst[64][64];  // [d][i]  (Q tile transposed)
  __shared__ float Kst[64][64];  // [d][j]  (K tile transposed)
  __shared__ float Vs[64][64];   // [m][j]
  __shared__ float Sst[64][64];  // [m][i]  (decayed scores, transposed)
  // reverse order: heaviest Q-tiles (most KV tiles) dispatch first
  const int qt = (int)gridDim.x - 1 - (int)blockIdx.x;
  const int h = blockIdx.y, b = blockIdx.z;
  const int t0 = qt * 64;
  const int tid = threadIdx.x, tx = tid & 15, ty = tid >> 4;
  const int rowbase = b * T_SEQ;
  const float gamma = 1.0f - exp2f(-5.0f - (float)h);
  const float lg = log2f(gamma);

  #pragma unroll
  for (int r = 0; r < 4; ++r) {
    int idx = r * 256 + tid;
    int i = idx >> 4, dq = idx & 15;
    float4 qv = *(const float4*)&Qg[(size_t)(rowbase + t0 + i) * DMODEL + h * DH + dq * 4];
    Qst[dq*4+0][i] = qv.x; Qst[dq*4+1][i] = qv.y;
    Qst[dq*4+2][i] = qv.z; Qst[dq*4+3][i] = qv.w;
  }

  float acc[4][4] = {{0.0f}};
  for (int mt = 0; mt <= qt; ++mt) {
    const int m0 = mt * 64;
    __syncthreads();  // prior iter's Sst/Vs reads done before overwrite
    #pragma unroll
    for (int r = 0; r < 4; ++r) {
      int idx = r * 256 + tid;
      int i = idx >> 4, dq = idx & 15;
      float4 kv = *(const float4*)&Kg[(size_t)(rowbase + m0 + i) * DMODEL + h * DH + dq * 4];
      Kst[dq*4+0][i] = kv.x; Kst[dq*4+1][i] = kv.y;
      Kst[dq*4+2][i] = kv.z; Kst[dq*4+3][i] = kv.w;
      float4 vv = *(const float4*)&Vg[(size_t)(rowbase + m0 + i) * DMODEL + h * DH + dq * 4];
      *(float4*)&Vs[i][dq*4] = vv;
    }
    __syncthreads();
    // S = Q @ K^T for this thread's 4x4 patch
    float s[4][4] = {{0.0f}};
    #pragma unroll
    for (int d = 0; d < 64; ++d) {
      float4 a = *(const float4*)&Qst[d][ty*4];
      float4 bb = *(const float4*)&Kst[d][tx*4];
      float avv[4] = {a.x, a.y, a.z, a.w};
      float bvv[4] = {bb.x, bb.y, bb.z, bb.w};
      #pragma unroll
      for (int ii = 0; ii < 4; ++ii)
        #pragma unroll
        for (int jj = 0; jj < 4; ++jj)
          s[ii][jj] = fmaf(avv[ii], bvv[jj], s[ii][jj]);
    }
    // decay + causal mask + 1/sqrt(dh); write transposed into Sst
    #pragma unroll
    for (int jj = 0; jj < 4; ++jj)
      #pragma unroll
      for (int ii = 0; ii < 4; ++ii) {
        int t = t0 + ty*4 + ii, m = m0 + tx*4 + jj;
        float val = 0.0f;
        if (m <= t) val = s[ii][jj] * 0.125f * exp2f((float)(t - m) * lg);
        Sst[tx*4+jj][ty*4+ii] = val;
      }
    __syncthreads();
    // O += S @ V
    #pragma unroll
    for (int m = 0; m < 64; ++m) {
      float4 a = *(const float4*)&Sst[m][ty*4];
      float4 bb = *(const float4*)&Vs[m][tx*4];
      float avv[4] = {a.x, a.y, a.z, a.w};
      float bvv[4] = {bb.x, bb.y, bb.z, bb.w};
      #pragma unroll
      for (int ii = 0; ii < 4; ++ii)
        #pragma unroll
        for (int jj = 0; jj < 4; ++jj)
          acc[ii][jj] = fmaf(avv[ii], bvv[jj], acc[ii][jj]);
    }
  }
  #pragma unroll
  for (int ii = 0; ii < 4; ++ii) {
    float4 o = make_float4(acc[ii][0], acc[ii][1], acc[ii][2], acc[ii][3]);
    *(float4*)&RET[(size_t)(rowbase + t0 + ty*4 + ii) * DMODEL + h * DH + tx*4] = o;
  }
}

// ---------------------------------------------------------------------------
// GroupNorm(8 groups of 64) + gate: S = silu(G + groupnorm(RET)*w + b).
// One block per (b,t) row; one wave (64 lanes) per group.
// ---------------------------------------------------------------------------
__global__ __launch_bounds__(512) void gn_gate_k(
    const float* __restrict__ RET, const float* __restrict__ Gg,
    const float* __restrict__ gw, const float* __restrict__ gb,
    float* __restrict__ S)
{
  const int row = blockIdx.x;
  const int tid = threadIdx.x;   // 0..511; wave index == group index
  const float r = RET[(size_t)row * DMODEL + tid];
  float sum = r, sq = r * r;
  #pragma unroll
  for (int off = 32; off > 0; off >>= 1) {
    sum += __shfl_xor(sum, off, 64);
    sq  += __shfl_xor(sq,  off, 64);
  }
  const float mean = sum * (1.0f / 64.0f);
  float var = sq * (1.0f / 64.0f) - mean * mean;
  var = fmaxf(var, 0.0f);
  const float rstd = rsqrtf(var + 1e-5f);
  const float normed = (r - mean) * rstd * gw[tid] + gb[tid];
  const float u = Gg[(size_t)row * DMODEL + tid] + normed;
  S[(size_t)row * DMODEL + tid] = u / (1.0f + expf(-u));
}

// ---------------------------------------------------------------------------
extern "C" void kernel_launch(void* const* d_in, const int* in_sizes, int n_in,
                              void* d_out, int out_size, void* d_ws, size_t ws_size,
                              hipStream_t stream) {
  const float* x   = (const float*)d_in[0];
  const float* WQ  = (const float*)d_in[1];
  const float* WK  = (const float*)d_in[2];
  const float* WV  = (const float*)d_in[3];
  const float* WG  = (const float*)d_in[4];
  const float* WO  = (const float*)d_in[5];
  const float* gnw = (const float*)d_in[6];
  const float* gnb = (const float*)d_in[7];
  float* out = (float*)d_out;

  const long MAT = (long)M_ROWS * DMODEL;  // 2,097,152 elements
  float* ws = (float*)d_ws;
  float* Q   = ws;
  float* K   = ws + MAT;
  float* V   = ws + 2 * MAT;
  float* G   = ws + 3 * MAT;
  float* RET = ws + 4 * MAT;
  float* Sb  = ws + 5 * MAT;

  // 1) fused projections: Q, K, V, G = x @ {W_Q, W_K, W_V, W_G}
  gemm512_k<<<dim3(DMODEL / 64, M_ROWS / 64, 4), 256, 0, stream>>>(
      x, WQ, WK, WV, WG, Q, MAT);
  // 2) retention
  retention_k<<<dim3(T_SEQ / 64, NH, 2), 256, 0, stream>>>(Q, K, V, RET);
  // 3) groupnorm + silu gate
  gn_gate_k<<<dim3(M_ROWS), 512, 0, stream>>>(RET, G, gnw, gnb, Sb);
  // 4) output projection
  gemm512_k<<<dim3(DMODEL / 64, M_ROWS / 64, 1), 256, 0, stream>>>(
      Sb, WO, WO, WO, WO, out, 0L);
}

// Round 2
// 302.139 us; speedup vs baseline: 14.2576x; 14.2576x over previous
//
#include <hip/hip_runtime.h>
#include <hip/hip_bf16.h>
#include <math.h>

#define DMODEL 512
#define T_SEQ 2048
#define NH 8
#define DH 64
#define M_ROWS 4096
#define LDST 72   // LDS row stride in bf16 elements (144 B = 36 dwords, pad 8)

typedef short s16x8 __attribute__((ext_vector_type(8)));
typedef float f32x4 __attribute__((ext_vector_type(4)));
typedef unsigned short u16x4 __attribute__((ext_vector_type(4)));

static __device__ __forceinline__ unsigned short f2bf(float f) {
  __hip_bfloat16 h = __float2bfloat16(f);
  return *(unsigned short*)&h;
}

// ---------------------------------------------------------------------------
// C = A(M x 512) @ W(512 x 512) GEMM, fp32 accumulate. z picks weight/output.
// Outputs z < nbf16 are written as bf16 (for Q,K,V), the rest fp32.
// ---------------------------------------------------------------------------
__global__ __launch_bounds__(256) void gemm512_k(
    const float* __restrict__ A,
    const float* __restrict__ W0, const float* __restrict__ W1,
    const float* __restrict__ W2, const float* __restrict__ W3,
    void* __restrict__ C0, void* __restrict__ C1,
    void* __restrict__ C2, void* __restrict__ C3, int nbf16)
{
  __shared__ float As[16][64];
  __shared__ float Bs[16][64];
  const int z = blockIdx.z;
  const float* W = (z == 0) ? W0 : (z == 1) ? W1 : (z == 2) ? W2 : W3;
  void* Cz      = (z == 0) ? C0 : (z == 1) ? C1 : (z == 2) ? C2 : C3;
  const int n0 = blockIdx.x * 64, m0 = blockIdx.y * 64;
  const int tid = threadIdx.x, tx = tid & 15, ty = tid >> 4;
  const int ai = tid >> 2, akq = tid & 3;
  const int bkk = tid >> 4, bnq = tid & 15;
  float acc[4][4] = {{0.0f}};
  for (int k0 = 0; k0 < 512; k0 += 16) {
    float4 av = *(const float4*)&A[(size_t)(m0 + ai) * DMODEL + k0 + akq * 4];
    float4 bv = *(const float4*)&W[(size_t)(k0 + bkk) * DMODEL + n0 + bnq * 4];
    As[akq*4+0][ai] = av.x; As[akq*4+1][ai] = av.y;
    As[akq*4+2][ai] = av.z; As[akq*4+3][ai] = av.w;
    *(float4*)&Bs[bkk][bnq*4] = bv;
    __syncthreads();
    #pragma unroll
    for (int kk = 0; kk < 16; ++kk) {
      float4 a = *(const float4*)&As[kk][ty*4];
      float4 b = *(const float4*)&Bs[kk][tx*4];
      float avv[4] = {a.x, a.y, a.z, a.w};
      float bvv[4] = {b.x, b.y, b.z, b.w};
      #pragma unroll
      for (int ii = 0; ii < 4; ++ii)
        #pragma unroll
        for (int jj = 0; jj < 4; ++jj)
          acc[ii][jj] = fmaf(avv[ii], bvv[jj], acc[ii][jj]);
    }
    __syncthreads();
  }
  if (z < nbf16) {
    unsigned short* Cb = (unsigned short*)Cz;
    #pragma unroll
    for (int ii = 0; ii < 4; ++ii) {
      u16x4 o;
      #pragma unroll
      for (int jj = 0; jj < 4; ++jj) o[jj] = f2bf(acc[ii][jj]);
      *(u16x4*)&Cb[(size_t)(m0 + ty*4 + ii) * DMODEL + n0 + tx*4] = o;
    }
  } else {
    float* Cf = (float*)Cz;
    #pragma unroll
    for (int ii = 0; ii < 4; ++ii) {
      float4 o = make_float4(acc[ii][0], acc[ii][1], acc[ii][2], acc[ii][3]);
      *(float4*)&Cf[(size_t)(m0 + ty*4 + ii) * DMODEL + n0 + tx*4] = o;
    }
  }
}

// ---------------------------------------------------------------------------
// Vt[b,h,d,t] = Vb[b,t,h,d]  (bf16 -> bf16, 64x64 tiles via LDS)
// ---------------------------------------------------------------------------
__global__ __launch_bounds__(256) void transpose_v_k(
    const unsigned short* __restrict__ Vb, unsigned short* __restrict__ Vt)
{
  __shared__ __align__(16) unsigned short buf[64 * LDST];
  const int t0 = blockIdx.x * 64;
  const int bh = blockIdx.y;           // b*8 + h
  const int b = bh >> 3, h = bh & 7;
  const int tid = threadIdx.x;
  const size_t inBase = ((size_t)b * T_SEQ) * DMODEL + (size_t)h * DH;
  const size_t outBase = (size_t)bh * DH * T_SEQ;
  #pragma unroll
  for (int r = 0; r < 2; ++r) {
    int idx = r * 256 + tid;
    int c = idx >> 6, i = idx & 63;    // c: d-chunk of 8, i: t row
    s16x8 v = *(const s16x8*)&Vb[inBase + (size_t)(t0 + i) * DMODEL + c * 8];
    #pragma unroll
    for (int e = 0; e < 8; ++e) buf[(c * 8 + e) * LDST + i] = ((unsigned short*)&v)[e];
  }
  __syncthreads();
  #pragma unroll
  for (int r = 0; r < 2; ++r) {
    int idx = r * 256 + tid;
    int d = idx >> 3, c2 = idx & 7;
    *(s16x8*)&Vt[outBase + (size_t)d * T_SEQ + t0 + c2 * 8] =
        *(const s16x8*)&buf[d * LDST + c2 * 8];
  }
}

// ---------------------------------------------------------------------------
// MFMA flash-retention. One block (256 thr = 4 waves) per (b, h, 64-row Q
// tile). Wave w owns S/O rows 16w..16w+15. QK^T -> decay (fp32, C-layout) ->
// P (bf16) via LDS -> PV, O accumulated in fp32 C fragments.
// ---------------------------------------------------------------------------
__global__ __launch_bounds__(256) void retention_mfma_k(
    const unsigned short* __restrict__ Qb, const unsigned short* __restrict__ Kb,
    const unsigned short* __restrict__ Vt, float* __restrict__ RET)
{
  __shared__ __align__(16) unsigned short Qs[64 * LDST];
  __shared__ __align__(16) unsigned short Ks[64 * LDST];
  __shared__ __align__(16) unsigned short Vs[64 * LDST];  // [d][m] (transposed)
  __shared__ __align__(16) unsigned short Ps[64 * LDST];  // [i][m]
  const int qt = (int)gridDim.x - 1 - (int)blockIdx.x;    // heavy tiles first
  const int h = blockIdx.y, b = blockIdx.z;
  const int t0 = qt * 64;
  const int tid = threadIdx.x;
  const int wave = tid >> 6, lane = tid & 63;
  const int n = lane & 15, quad = lane >> 4;
  const size_t qkBase = ((size_t)b * T_SEQ) * DMODEL + (size_t)h * DH;
  const size_t vtBase = (size_t)(b * NH + h) * DH * T_SEQ;
  const float gamma = 1.0f - exp2f(-5.0f - (float)h);
  const float lg = log2f(gamma);

  // stage Q tile (rows t0..t0+63)
  #pragma unroll
  for (int r = 0; r < 2; ++r) {
    int idx = r * 256 + tid;
    int i = idx >> 3, c = idx & 7;
    *(s16x8*)&Qs[i * LDST + c * 8] =
        *(const s16x8*)&Qb[qkBase + (size_t)(t0 + i) * DMODEL + c * 8];
  }

  // per-lane decay factors: gamma^(row) and gamma^(-col)
  float rowf[4], colf[4];
  #pragma unroll
  for (int r = 0; r < 4; ++r) rowf[r] = exp2f((float)(wave*16 + quad*4 + r) * lg);
  #pragma unroll
  for (int j = 0; j < 4; ++j) colf[j] = exp2f(-(float)(j*16 + n) * lg);

  f32x4 acc[4];
  #pragma unroll
  for (int j = 0; j < 4; ++j) acc[j] = (f32x4){0.f, 0.f, 0.f, 0.f};

  for (int mt = 0; mt <= qt; ++mt) {
    const int m0 = mt * 64;
    __syncthreads();  // protect Ks/Vs (and Qs on iter 0) before restage
    #pragma unroll
    for (int r = 0; r < 2; ++r) {
      int idx = r * 256 + tid;
      int i = idx >> 3, c = idx & 7;
      *(s16x8*)&Ks[i * LDST + c * 8] =
          *(const s16x8*)&Kb[qkBase + (size_t)(m0 + i) * DMODEL + c * 8];
      *(s16x8*)&Vs[i * LDST + c * 8] =
          *(const s16x8*)&Vt[vtBase + (size_t)i * T_SEQ + m0 + c * 8];
    }
    __syncthreads();

    // S = Q @ K^T  (wave strip rows 16w.., 4 col tiles, K-dim 64 = 2 steps)
    f32x4 s[4];
    #pragma unroll
    for (int j = 0; j < 4; ++j) s[j] = (f32x4){0.f, 0.f, 0.f, 0.f};
    #pragma unroll
    for (int kk = 0; kk < 2; ++kk) {
      s16x8 a = *(const s16x8*)&Qs[(wave*16 + n) * LDST + kk*32 + quad*8];
      #pragma unroll
      for (int j = 0; j < 4; ++j) {
        s16x8 bf = *(const s16x8*)&Ks[(j*16 + n) * LDST + kk*32 + quad*8];
        s[j] = __builtin_amdgcn_mfma_f32_16x16x32_bf16(a, bf, s[j], 0, 0, 0);
      }
    }

    // decay + causal mask; P (bf16) -> Ps[i][m]
    const float base = 0.125f * exp2f((float)(t0 - m0) * lg);
    const bool diag = (mt == qt);
    #pragma unroll
    for (int j = 0; j < 4; ++j) {
      #pragma unroll
      for (int r = 0; r < 4; ++r) {
        int i = wave*16 + quad*4 + r;   // row in 64x64 S tile
        int mcol = j*16 + n;            // col in tile
        float v = s[j][r] * base * rowf[r] * colf[j];
        if (diag && i < mcol) v = 0.0f;
        Ps[i * LDST + mcol] = f2bf(v);
      }
    }
    __syncthreads();

    // O += P @ V   (A = Ps rows 16w+n, k=mcol; B = Vs[d=16j+n][mcol])
    #pragma unroll
    for (int kk = 0; kk < 2; ++kk) {
      s16x8 a = *(const s16x8*)&Ps[(wave*16 + n) * LDST + kk*32 + quad*8];
      #pragma unroll
      for (int j = 0; j < 4; ++j) {
        s16x8 bf = *(const s16x8*)&Vs[(j*16 + n) * LDST + kk*32 + quad*8];
        acc[j] = __builtin_amdgcn_mfma_f32_16x16x32_bf16(a, bf, acc[j], 0, 0, 0);
      }
    }
  }

  // write O: row = t0 + 16w + 4*quad + r, col = h*64 + 16j + n
  #pragma unroll
  for (int j = 0; j < 4; ++j)
    #pragma unroll
    for (int r = 0; r < 4; ++r)
      RET[((size_t)b * T_SEQ + t0 + wave*16 + quad*4 + r) * DMODEL + h*DH + j*16 + n] =
          acc[j][r];
}

// ---------------------------------------------------------------------------
// GroupNorm(8 groups of 64) + gate: S = silu(G + groupnorm(RET)*w + b)
// ---------------------------------------------------------------------------
__global__ __launch_bounds__(512) void gn_gate_k(
    const float* __restrict__ RET, const float* __restrict__ Gg,
    const float* __restrict__ gw, const float* __restrict__ gb,
    float* __restrict__ S)
{
  const int row = blockIdx.x;
  const int tid = threadIdx.x;
  const float r = RET[(size_t)row * DMODEL + tid];
  float sum = r, sq = r * r;
  #pragma unroll
  for (int off = 32; off > 0; off >>= 1) {
    sum += __shfl_xor(sum, off, 64);
    sq  += __shfl_xor(sq,  off, 64);
  }
  const float mean = sum * (1.0f / 64.0f);
  float var = sq * (1.0f / 64.0f) - mean * mean;
  var = fmaxf(var, 0.0f);
  const float rstd = rsqrtf(var + 1e-5f);
  const float normed = (r - mean) * rstd * gw[tid] + gb[tid];
  const float u = Gg[(size_t)row * DMODEL + tid] + normed;
  S[(size_t)row * DMODEL + tid] = u / (1.0f + expf(-u));
}

// ---------------------------------------------------------------------------
extern "C" void kernel_launch(void* const* d_in, const int* in_sizes, int n_in,
                              void* d_out, int out_size, void* d_ws, size_t ws_size,
                              hipStream_t stream) {
  const float* x   = (const float*)d_in[0];
  const float* WQ  = (const float*)d_in[1];
  const float* WK  = (const float*)d_in[2];
  const float* WV  = (const float*)d_in[3];
  const float* WG  = (const float*)d_in[4];
  const float* WO  = (const float*)d_in[5];
  const float* gnw = (const float*)d_in[6];
  const float* gnb = (const float*)d_in[7];
  float* out = (float*)d_out;

  const size_t MAT = (size_t)M_ROWS * DMODEL;  // 2,097,152 elements
  char* ws = (char*)d_ws;
  unsigned short* Qb = (unsigned short*)(ws);                 // 4 MB
  unsigned short* Kb = (unsigned short*)(ws + 4  * (1<<20));  // 4 MB
  unsigned short* Vb = (unsigned short*)(ws + 8  * (1<<20));  // 4 MB
  unsigned short* Vt = (unsigned short*)(ws + 12 * (1<<20));  // 4 MB
  float* G   = (float*)(ws + 16 * (1<<20));                   // 8 MB
  float* RET = (float*)(ws + 24 * (1<<20));                   // 8 MB
  float* Sb  = (float*)(ws + 32 * (1<<20));                   // 8 MB
  (void)MAT; (void)ws_size;

  // 1) projections: Qb,Kb,Vb (bf16) + G (fp32)
  gemm512_k<<<dim3(DMODEL/64, M_ROWS/64, 4), 256, 0, stream>>>(
      x, WQ, WK, WV, WG, Qb, Kb, Vb, G, 3);
  // 2) V transpose to (b,h,d,t)
  transpose_v_k<<<dim3(T_SEQ/64, NH*2), 256, 0, stream>>>(Vb, Vt);
  // 3) retention (MFMA)
  retention_mfma_k<<<dim3(T_SEQ/64, NH, 2), 256, 0, stream>>>(Qb, Kb, Vt, RET);
  // 4) groupnorm + silu gate
  gn_gate_k<<<dim3(M_ROWS), 512, 0, stream>>>(RET, G, gnw, gnb, Sb);
  // 5) output projection (fp32)
  gemm512_k<<<dim3(DMODEL/64, M_ROWS/64, 1), 256, 0, stream>>>(
      Sb, WO, WO, WO, WO, out, out, out, out, 0);
}

// Round 3
// 184.316 us; speedup vs baseline: 23.3717x; 1.6392x over previous
//
#include <hip/hip_runtime.h>
#include <hip/hip_bf16.h>
#include <math.h>

#define DMODEL 512
#define T_SEQ 2048
#define NH 8
#define DH 64
#define M_ROWS 4096
#define LDST 72   // padded LDS row stride (bf16 elems): 2-way bank alias = free

typedef short s16x8 __attribute__((ext_vector_type(8)));
typedef float f32x4 __attribute__((ext_vector_type(4)));

static __device__ __forceinline__ unsigned short f2bf(float f) {
  __hip_bfloat16 h = __float2bfloat16(f);
  return *(unsigned short*)&h;
}

// ---------------------------------------------------------------------------
// x (fp32, M x 512) -> bf16
// ---------------------------------------------------------------------------
__global__ __launch_bounds__(256) void cast_x_k(
    const float* __restrict__ x, unsigned short* __restrict__ Xb)
{
  const size_t i = ((size_t)blockIdx.x * 256 + threadIdx.x) * 8;
  float4 a = *(const float4*)&x[i];
  float4 b = *(const float4*)&x[i + 4];
  s16x8 o;
  o[0]=f2bf(a.x); o[1]=f2bf(a.y); o[2]=f2bf(a.z); o[3]=f2bf(a.w);
  o[4]=f2bf(b.x); o[5]=f2bf(b.y); o[6]=f2bf(b.z); o[7]=f2bf(b.w);
  *(s16x8*)&Xb[i] = o;
}

// ---------------------------------------------------------------------------
// WT[z*512 + n][k] = W_z[k][n]  (fp32 -> bf16), 64x64 tiles via LDS
// ---------------------------------------------------------------------------
__global__ __launch_bounds__(256) void prep_w_k(
    const float* __restrict__ W0, const float* __restrict__ W1,
    const float* __restrict__ W2, const float* __restrict__ W3,
    const float* __restrict__ W4, unsigned short* __restrict__ WT)
{
  __shared__ __align__(16) unsigned short buf[64 * LDST];  // buf[n][k]
  const int n0 = blockIdx.x * 64, k0 = blockIdx.y * 64, z = blockIdx.z;
  const float* W = (z==0)?W0:(z==1)?W1:(z==2)?W2:(z==3)?W3:W4;
  const int tid = threadIdx.x;
  #pragma unroll
  for (int r = 0; r < 4; ++r) {
    int idx = r * 256 + tid;
    int kr = idx >> 4, nc = idx & 15;
    float4 v = *(const float4*)&W[(size_t)(k0 + kr) * DMODEL + n0 + nc * 4];
    buf[(nc*4+0) * LDST + kr] = f2bf(v.x);
    buf[(nc*4+1) * LDST + kr] = f2bf(v.y);
    buf[(nc*4+2) * LDST + kr] = f2bf(v.z);
    buf[(nc*4+3) * LDST + kr] = f2bf(v.w);
  }
  __syncthreads();
  #pragma unroll
  for (int r = 0; r < 2; ++r) {
    int idx = r * 256 + tid;
    int nr = idx >> 3, c = idx & 7;
    *(s16x8*)&WT[((size_t)z * DMODEL + n0 + nr) * DMODEL + k0 + c * 8] =
        *(const s16x8*)&buf[nr * LDST + c * 8];
  }
}

// ---------------------------------------------------------------------------
// C = A(M x 512, bf16) @ BT^T where BT is [Nstack][512] bf16 (rows = output
// cols). 128x128 tile, BK=64, 4 waves in 2x2, each 64x64 via 16x16x32 MFMA.
// z = stacked-N / 512 selects output; z < nbf16 stores bf16 else fp32.
// ---------------------------------------------------------------------------
__global__ __launch_bounds__(256) void mfma_gemm_k(
    const unsigned short* __restrict__ A, const unsigned short* __restrict__ BT,
    void* __restrict__ C0, void* __restrict__ C1,
    void* __restrict__ C2, void* __restrict__ C3, int nbf16)
{
  __shared__ __align__(16) unsigned short As[128 * LDST];
  __shared__ __align__(16) unsigned short Bs[128 * LDST];
  const int ng0 = blockIdx.x * 128;       // stacked col base
  const int m0 = blockIdx.y * 128;
  const int z = ng0 >> 9, n0 = ng0 & 511; // output id, col within output
  void* Cz = (z==0)?C0:(z==1)?C1:(z==2)?C2:C3;
  const int tid = threadIdx.x;
  const int wave = tid >> 6, lane = tid & 63;
  const int wm = wave >> 1, wn = wave & 1;
  const int n = lane & 15, quad = lane >> 4;

  f32x4 acc[4][4];
  #pragma unroll
  for (int mi = 0; mi < 4; ++mi)
    #pragma unroll
    for (int ni = 0; ni < 4; ++ni) acc[mi][ni] = (f32x4){0.f,0.f,0.f,0.f};

  for (int k0 = 0; k0 < 512; k0 += 64) {
    #pragma unroll
    for (int r = 0; r < 4; ++r) {
      int idx = r * 256 + tid;
      int row = idx >> 3, c = idx & 7;
      *(s16x8*)&As[row * LDST + c * 8] =
          *(const s16x8*)&A[(size_t)(m0 + row) * DMODEL + k0 + c * 8];
      *(s16x8*)&Bs[row * LDST + c * 8] =
          *(const s16x8*)&BT[(size_t)(ng0 + row) * DMODEL + k0 + c * 8];
    }
    __syncthreads();
    #pragma unroll
    for (int kk = 0; kk < 2; ++kk) {
      s16x8 af[4], bf[4];
      #pragma unroll
      for (int mi = 0; mi < 4; ++mi)
        af[mi] = *(const s16x8*)&As[(wm*64 + mi*16 + n) * LDST + kk*32 + quad*8];
      #pragma unroll
      for (int ni = 0; ni < 4; ++ni)
        bf[ni] = *(const s16x8*)&Bs[(wn*64 + ni*16 + n) * LDST + kk*32 + quad*8];
      #pragma unroll
      for (int mi = 0; mi < 4; ++mi)
        #pragma unroll
        for (int ni = 0; ni < 4; ++ni)
          acc[mi][ni] = __builtin_amdgcn_mfma_f32_16x16x32_bf16(
              af[mi], bf[ni], acc[mi][ni], 0, 0, 0);
    }
    __syncthreads();
  }

  // epilogue: row = m0+wm*64+mi*16+quad*4+r, col = n0+wn*64+ni*16+n
  if (z < nbf16) {
    unsigned short* Cb = (unsigned short*)Cz;
    #pragma unroll
    for (int mi = 0; mi < 4; ++mi)
      #pragma unroll
      for (int ni = 0; ni < 4; ++ni)
        #pragma unroll
        for (int r = 0; r < 4; ++r)
          Cb[(size_t)(m0 + wm*64 + mi*16 + quad*4 + r) * DMODEL +
             n0 + wn*64 + ni*16 + n] = f2bf(acc[mi][ni][r]);
  } else {
    float* Cf = (float*)Cz;
    #pragma unroll
    for (int mi = 0; mi < 4; ++mi)
      #pragma unroll
      for (int ni = 0; ni < 4; ++ni)
        #pragma unroll
        for (int r = 0; r < 4; ++r)
          Cf[(size_t)(m0 + wm*64 + mi*16 + quad*4 + r) * DMODEL +
             n0 + wn*64 + ni*16 + n] = acc[mi][ni][r];
  }
}

// ---------------------------------------------------------------------------
// Vt[b,h,d,t] = Vb[b,t,h,d]  (bf16 -> bf16, 64x64 tiles via LDS)
// ---------------------------------------------------------------------------
__global__ __launch_bounds__(256) void transpose_v_k(
    const unsigned short* __restrict__ Vb, unsigned short* __restrict__ Vt)
{
  __shared__ __align__(16) unsigned short buf[64 * LDST];
  const int t0 = blockIdx.x * 64;
  const int bh = blockIdx.y;
  const int b = bh >> 3, h = bh & 7;
  const int tid = threadIdx.x;
  const size_t inBase = ((size_t)b * T_SEQ) * DMODEL + (size_t)h * DH;
  const size_t outBase = (size_t)bh * DH * T_SEQ;
  #pragma unroll
  for (int r = 0; r < 2; ++r) {
    int idx = r * 256 + tid;
    int c = idx >> 6, i = idx & 63;
    s16x8 v = *(const s16x8*)&Vb[inBase + (size_t)(t0 + i) * DMODEL + c * 8];
    #pragma unroll
    for (int e = 0; e < 8; ++e) buf[(c * 8 + e) * LDST + i] = ((unsigned short*)&v)[e];
  }
  __syncthreads();
  #pragma unroll
  for (int r = 0; r < 2; ++r) {
    int idx = r * 256 + tid;
    int d = idx >> 3, c2 = idx & 7;
    *(s16x8*)&Vt[outBase + (size_t)d * T_SEQ + t0 + c2 * 8] =
        *(const s16x8*)&buf[d * LDST + c2 * 8];
  }
}

// ---------------------------------------------------------------------------
// MFMA flash-retention (unchanged from round 2).
// ---------------------------------------------------------------------------
__global__ __launch_bounds__(256) void retention_mfma_k(
    const unsigned short* __restrict__ Qb, const unsigned short* __restrict__ Kb,
    const unsigned short* __restrict__ Vt, float* __restrict__ RET)
{
  __shared__ __align__(16) unsigned short Qs[64 * LDST];
  __shared__ __align__(16) unsigned short Ks[64 * LDST];
  __shared__ __align__(16) unsigned short Vs[64 * LDST];
  __shared__ __align__(16) unsigned short Ps[64 * LDST];
  const int qt = (int)gridDim.x - 1 - (int)blockIdx.x;
  const int h = blockIdx.y, b = blockIdx.z;
  const int t0 = qt * 64;
  const int tid = threadIdx.x;
  const int wave = tid >> 6, lane = tid & 63;
  const int n = lane & 15, quad = lane >> 4;
  const size_t qkBase = ((size_t)b * T_SEQ) * DMODEL + (size_t)h * DH;
  const size_t vtBase = (size_t)(b * NH + h) * DH * T_SEQ;
  const float gamma = 1.0f - exp2f(-5.0f - (float)h);
  const float lg = log2f(gamma);

  #pragma unroll
  for (int r = 0; r < 2; ++r) {
    int idx = r * 256 + tid;
    int i = idx >> 3, c = idx & 7;
    *(s16x8*)&Qs[i * LDST + c * 8] =
        *(const s16x8*)&Qb[qkBase + (size_t)(t0 + i) * DMODEL + c * 8];
  }

  float rowf[4], colf[4];
  #pragma unroll
  for (int r = 0; r < 4; ++r) rowf[r] = exp2f((float)(wave*16 + quad*4 + r) * lg);
  #pragma unroll
  for (int j = 0; j < 4; ++j) colf[j] = exp2f(-(float)(j*16 + n) * lg);

  f32x4 acc[4];
  #pragma unroll
  for (int j = 0; j < 4; ++j) acc[j] = (f32x4){0.f, 0.f, 0.f, 0.f};

  for (int mt = 0; mt <= qt; ++mt) {
    const int m0 = mt * 64;
    __syncthreads();
    #pragma unroll
    for (int r = 0; r < 2; ++r) {
      int idx = r * 256 + tid;
      int i = idx >> 3, c = idx & 7;
      *(s16x8*)&Ks[i * LDST + c * 8] =
          *(const s16x8*)&Kb[qkBase + (size_t)(m0 + i) * DMODEL + c * 8];
      *(s16x8*)&Vs[i * LDST + c * 8] =
          *(const s16x8*)&Vt[vtBase + (size_t)i * T_SEQ + m0 + c * 8];
    }
    __syncthreads();

    f32x4 s[4];
    #pragma unroll
    for (int j = 0; j < 4; ++j) s[j] = (f32x4){0.f, 0.f, 0.f, 0.f};
    #pragma unroll
    for (int kk = 0; kk < 2; ++kk) {
      s16x8 a = *(const s16x8*)&Qs[(wave*16 + n) * LDST + kk*32 + quad*8];
      #pragma unroll
      for (int j = 0; j < 4; ++j) {
        s16x8 bf = *(const s16x8*)&Ks[(j*16 + n) * LDST + kk*32 + quad*8];
        s[j] = __builtin_amdgcn_mfma_f32_16x16x32_bf16(a, bf, s[j], 0, 0, 0);
      }
    }

    const float base = 0.125f * exp2f((float)(t0 - m0) * lg);
    const bool diag = (mt == qt);
    #pragma unroll
    for (int j = 0; j < 4; ++j) {
      #pragma unroll
      for (int r = 0; r < 4; ++r) {
        int i = wave*16 + quad*4 + r;
        int mcol = j*16 + n;
        float v = s[j][r] * base * rowf[r] * colf[j];
        if (diag && i < mcol) v = 0.0f;
        Ps[i * LDST + mcol] = f2bf(v);
      }
    }
    __syncthreads();

    #pragma unroll
    for (int kk = 0; kk < 2; ++kk) {
      s16x8 a = *(const s16x8*)&Ps[(wave*16 + n) * LDST + kk*32 + quad*8];
      #pragma unroll
      for (int j = 0; j < 4; ++j) {
        s16x8 bf = *(const s16x8*)&Vs[(j*16 + n) * LDST + kk*32 + quad*8];
        acc[j] = __builtin_amdgcn_mfma_f32_16x16x32_bf16(a, bf, acc[j], 0, 0, 0);
      }
    }
  }

  #pragma unroll
  for (int j = 0; j < 4; ++j)
    #pragma unroll
    for (int r = 0; r < 4; ++r)
      RET[((size_t)b * T_SEQ + t0 + wave*16 + quad*4 + r) * DMODEL + h*DH + j*16 + n] =
          acc[j][r];
}

// ---------------------------------------------------------------------------
// GroupNorm + gate: Sb = silu(G + gn(RET)*w + b), emitted as bf16
// ---------------------------------------------------------------------------
__global__ __launch_bounds__(512) void gn_gate_k(
    const float* __restrict__ RET, const float* __restrict__ Gg,
    const float* __restrict__ gw, const float* __restrict__ gb,
    unsigned short* __restrict__ S)
{
  const int row = blockIdx.x;
  const int tid = threadIdx.x;
  const float r = RET[(size_t)row * DMODEL + tid];
  float sum = r, sq = r * r;
  #pragma unroll
  for (int off = 32; off > 0; off >>= 1) {
    sum += __shfl_xor(sum, off, 64);
    sq  += __shfl_xor(sq,  off, 64);
  }
  const float mean = sum * (1.0f / 64.0f);
  float var = sq * (1.0f / 64.0f) - mean * mean;
  var = fmaxf(var, 0.0f);
  const float rstd = rsqrtf(var + 1e-5f);
  const float normed = (r - mean) * rstd * gw[tid] + gb[tid];
  const float u = Gg[(size_t)row * DMODEL + tid] + normed;
  S[(size_t)row * DMODEL + tid] = f2bf(u / (1.0f + expf(-u)));
}

// ---------------------------------------------------------------------------
extern "C" void kernel_launch(void* const* d_in, const int* in_sizes, int n_in,
                              void* d_out, int out_size, void* d_ws, size_t ws_size,
                              hipStream_t stream) {
  const float* x   = (const float*)d_in[0];
  const float* WQ  = (const float*)d_in[1];
  const float* WK  = (const float*)d_in[2];
  const float* WV  = (const float*)d_in[3];
  const float* WG  = (const float*)d_in[4];
  const float* WO  = (const float*)d_in[5];
  const float* gnw = (const float*)d_in[6];
  const float* gnb = (const float*)d_in[7];
  float* out = (float*)d_out;

  char* ws = (char*)d_ws;
  unsigned short* Xb = (unsigned short*)(ws);                 // 4 MB
  unsigned short* Qb = (unsigned short*)(ws + 4  * (1<<20));  // 4 MB
  unsigned short* Kb = (unsigned short*)(ws + 8  * (1<<20));  // 4 MB
  unsigned short* Vb = (unsigned short*)(ws + 12 * (1<<20));  // 4 MB
  unsigned short* Vt = (unsigned short*)(ws + 16 * (1<<20));  // 4 MB
  float* G   = (float*)(ws + 20 * (1<<20));                   // 8 MB
  float* RET = (float*)(ws + 28 * (1<<20));                   // 8 MB
  unsigned short* Sb = (unsigned short*)(ws + 36 * (1<<20));  // 4 MB
  unsigned short* WT = (unsigned short*)(ws + 40 * (1<<20));  // 2.5 MB
  (void)ws_size;

  // 0) casts / weight transposes
  cast_x_k<<<dim3(M_ROWS * DMODEL / (256 * 8)), 256, 0, stream>>>(x, Xb);
  prep_w_k<<<dim3(8, 8, 5), 256, 0, stream>>>(WQ, WK, WV, WG, WO, WT);
  // 1) fused projections (stacked N=2048): Qb,Kb,Vb bf16 + G fp32
  mfma_gemm_k<<<dim3(16, M_ROWS / 128), 256, 0, stream>>>(
      Xb, WT, Qb, Kb, Vb, G, 3);
  // 2) V transpose to (b,h,d,t)
  transpose_v_k<<<dim3(T_SEQ / 64, NH * 2), 256, 0, stream>>>(Vb, Vt);
  // 3) retention (MFMA)
  retention_mfma_k<<<dim3(T_SEQ / 64, NH, 2), 256, 0, stream>>>(Qb, Kb, Vt, RET);
  // 4) groupnorm + silu gate -> bf16
  gn_gate_k<<<dim3(M_ROWS), 512, 0, stream>>>(RET, G, gnw, gnb, Sb);
  // 5) output projection (fp32 out)
  mfma_gemm_k<<<dim3(4, M_ROWS / 128), 256, 0, stream>>>(
      Sb, WT + 4 * DMODEL * DMODEL, out, out, out, out, 0);
}

// Round 4
// 128.378 us; speedup vs baseline: 33.5554x; 1.4357x over previous
//
#include <hip/hip_runtime.h>
#include <hip/hip_bf16.h>
#include <math.h>

#define DMODEL 512
#define T_SEQ 2048
#define NH 8
#define DH 64
#define M_ROWS 4096
#define LDST 72   // padded LDS row stride (bf16 elems): 2-way bank alias = free

typedef short s16x8 __attribute__((ext_vector_type(8)));
typedef float f32x4 __attribute__((ext_vector_type(4)));
typedef unsigned short u16x4 __attribute__((ext_vector_type(4)));

static __device__ __forceinline__ unsigned short f2bf(float f) {
  __hip_bfloat16 h = __float2bfloat16(f);
  return *(unsigned short*)&h;
}
static __device__ __forceinline__ float bf2f(unsigned short u) {
  union { unsigned int i; float f; } x; x.i = (unsigned int)u << 16; return x.f;
}

// ---------------------------------------------------------------------------
// x (fp32, M x 512) -> bf16
// ---------------------------------------------------------------------------
__global__ __launch_bounds__(256) void cast_x_k(
    const float* __restrict__ x, unsigned short* __restrict__ Xb)
{
  const size_t i = ((size_t)blockIdx.x * 256 + threadIdx.x) * 8;
  float4 a = *(const float4*)&x[i];
  float4 b = *(const float4*)&x[i + 4];
  s16x8 o;
  o[0]=f2bf(a.x); o[1]=f2bf(a.y); o[2]=f2bf(a.z); o[3]=f2bf(a.w);
  o[4]=f2bf(b.x); o[5]=f2bf(b.y); o[6]=f2bf(b.z); o[7]=f2bf(b.w);
  *(s16x8*)&Xb[i] = o;
}

// ---------------------------------------------------------------------------
// WT[z*512 + n][k] = W_z[k][n]  (fp32 -> bf16), 64x64 tiles via LDS
// ---------------------------------------------------------------------------
__global__ __launch_bounds__(256) void prep_w_k(
    const float* __restrict__ W0, const float* __restrict__ W1,
    const float* __restrict__ W2, const float* __restrict__ W3,
    const float* __restrict__ W4, unsigned short* __restrict__ WT)
{
  __shared__ __align__(16) unsigned short buf[64 * LDST];  // buf[n][k]
  const int n0 = blockIdx.x * 64, k0 = blockIdx.y * 64, z = blockIdx.z;
  const float* W = (z==0)?W0:(z==1)?W1:(z==2)?W2:(z==3)?W3:W4;
  const int tid = threadIdx.x;
  #pragma unroll
  for (int r = 0; r < 4; ++r) {
    int idx = r * 256 + tid;
    int kr = idx >> 4, nc = idx & 15;
    float4 v = *(const float4*)&W[(size_t)(k0 + kr) * DMODEL + n0 + nc * 4];
    buf[(nc*4+0) * LDST + kr] = f2bf(v.x);
    buf[(nc*4+1) * LDST + kr] = f2bf(v.y);
    buf[(nc*4+2) * LDST + kr] = f2bf(v.z);
    buf[(nc*4+3) * LDST + kr] = f2bf(v.w);
  }
  __syncthreads();
  #pragma unroll
  for (int r = 0; r < 2; ++r) {
    int idx = r * 256 + tid;
    int nr = idx >> 3, c = idx & 7;
    *(s16x8*)&WT[((size_t)z * DMODEL + n0 + nr) * DMODEL + k0 + c * 8] =
        *(const s16x8*)&buf[nr * LDST + c * 8];
  }
}

// ---------------------------------------------------------------------------
// C = A(M x 512, bf16) @ BT^T, 128x128 tile, BK=64, 2x2 waves of 64x64.
// z = stacked-N / 512 selects output; z < nbf16 stores bf16 else fp32.
// ---------------------------------------------------------------------------
__global__ __launch_bounds__(256) void mfma_gemm_k(
    const unsigned short* __restrict__ A, const unsigned short* __restrict__ BT,
    void* __restrict__ C0, void* __restrict__ C1,
    void* __restrict__ C2, void* __restrict__ C3, int nbf16)
{
  __shared__ __align__(16) unsigned short As[128 * LDST];
  __shared__ __align__(16) unsigned short Bs[128 * LDST];
  const int ng0 = blockIdx.x * 128;
  const int m0 = blockIdx.y * 128;
  const int z = ng0 >> 9, n0 = ng0 & 511;
  void* Cz = (z==0)?C0:(z==1)?C1:(z==2)?C2:C3;
  const int tid = threadIdx.x;
  const int wave = tid >> 6, lane = tid & 63;
  const int wm = wave >> 1, wn = wave & 1;
  const int n = lane & 15, quad = lane >> 4;

  f32x4 acc[4][4];
  #pragma unroll
  for (int mi = 0; mi < 4; ++mi)
    #pragma unroll
    for (int ni = 0; ni < 4; ++ni) acc[mi][ni] = (f32x4){0.f,0.f,0.f,0.f};

  for (int k0 = 0; k0 < 512; k0 += 64) {
    #pragma unroll
    for (int r = 0; r < 4; ++r) {
      int idx = r * 256 + tid;
      int row = idx >> 3, c = idx & 7;
      *(s16x8*)&As[row * LDST + c * 8] =
          *(const s16x8*)&A[(size_t)(m0 + row) * DMODEL + k0 + c * 8];
      *(s16x8*)&Bs[row * LDST + c * 8] =
          *(const s16x8*)&BT[(size_t)(ng0 + row) * DMODEL + k0 + c * 8];
    }
    __syncthreads();
    #pragma unroll
    for (int kk = 0; kk < 2; ++kk) {
      s16x8 af[4], bf[4];
      #pragma unroll
      for (int mi = 0; mi < 4; ++mi)
        af[mi] = *(const s16x8*)&As[(wm*64 + mi*16 + n) * LDST + kk*32 + quad*8];
      #pragma unroll
      for (int ni = 0; ni < 4; ++ni)
        bf[ni] = *(const s16x8*)&Bs[(wn*64 + ni*16 + n) * LDST + kk*32 + quad*8];
      #pragma unroll
      for (int mi = 0; mi < 4; ++mi)
        #pragma unroll
        for (int ni = 0; ni < 4; ++ni)
          acc[mi][ni] = __builtin_amdgcn_mfma_f32_16x16x32_bf16(
              af[mi], bf[ni], acc[mi][ni], 0, 0, 0);
    }
    __syncthreads();
  }

  if (z < nbf16) {
    unsigned short* Cb = (unsigned short*)Cz;
    #pragma unroll
    for (int mi = 0; mi < 4; ++mi)
      #pragma unroll
      for (int ni = 0; ni < 4; ++ni)
        #pragma unroll
        for (int r = 0; r < 4; ++r)
          Cb[(size_t)(m0 + wm*64 + mi*16 + quad*4 + r) * DMODEL +
             n0 + wn*64 + ni*16 + n] = f2bf(acc[mi][ni][r]);
  } else {
    float* Cf = (float*)Cz;
    #pragma unroll
    for (int mi = 0; mi < 4; ++mi)
      #pragma unroll
      for (int ni = 0; ni < 4; ++ni)
        #pragma unroll
        for (int r = 0; r < 4; ++r)
          Cf[(size_t)(m0 + wm*64 + mi*16 + quad*4 + r) * DMODEL +
             n0 + wn*64 + ni*16 + n] = acc[mi][ni][r];
  }
}

// ---------------------------------------------------------------------------
// Chunked retention stage 1: per (b,h,chunk) decayed KV outer product
//   AT[bh][c][d2][d1] = sum_m gamma^(64-m) K[m][d1] V[m][d2]   (fp32)
// ---------------------------------------------------------------------------
__global__ __launch_bounds__(256) void ret_kv_k(
    const unsigned short* __restrict__ Kb, const unsigned short* __restrict__ Vb,
    float* __restrict__ AT)
{
  __shared__ __align__(16) unsigned short Kts[64 * LDST]; // [d1][m], scaled
  __shared__ __align__(16) unsigned short Vts[64 * LDST]; // [d2][m]
  const int c = blockIdx.x, h = blockIdx.y, b = blockIdx.z;
  const int bh = b * NH + h;
  const int tid = threadIdx.x;
  const int wave = tid >> 6, lane = tid & 63;
  const int n = lane & 15, quad = lane >> 4;
  const size_t base = ((size_t)b * T_SEQ + (size_t)c * 64) * DMODEL + h * DH;
  const float lg = log2f(1.0f - exp2f(-5.0f - (float)h));

  #pragma unroll
  for (int r = 0; r < 2; ++r) {
    int idx = r * 256 + tid;
    int m = idx & 63, ch = idx >> 6;   // m inner: conflict-free LDS scatter
    s16x8 kv = *(const s16x8*)&Kb[base + (size_t)m * DMODEL + ch * 8];
    s16x8 vv = *(const s16x8*)&Vb[base + (size_t)m * DMODEL + ch * 8];
    float sc = exp2f((float)(64 - m) * lg);
    #pragma unroll
    for (int e = 0; e < 8; ++e) {
      Kts[(ch * 8 + e) * LDST + m] = f2bf(bf2f(((unsigned short*)&kv)[e]) * sc);
      Vts[(ch * 8 + e) * LDST + m] = ((unsigned short*)&vv)[e];
    }
  }
  __syncthreads();

  f32x4 at[4];
  #pragma unroll
  for (int j = 0; j < 4; ++j) at[j] = (f32x4){0.f,0.f,0.f,0.f};
  #pragma unroll
  for (int kk = 0; kk < 2; ++kk) {
    s16x8 a = *(const s16x8*)&Vts[(wave*16 + n) * LDST + kk*32 + quad*8];
    #pragma unroll
    for (int j = 0; j < 4; ++j) {
      s16x8 bf = *(const s16x8*)&Kts[(j*16 + n) * LDST + kk*32 + quad*8];
      at[j] = __builtin_amdgcn_mfma_f32_16x16x32_bf16(a, bf, at[j], 0, 0, 0);
    }
  }
  float* Ab = AT + (((size_t)bh * 32 + c) << 12);
  #pragma unroll
  for (int j = 0; j < 4; ++j)
    #pragma unroll
    for (int r = 0; r < 4; ++r)
      Ab[(wave*16 + quad*4 + r) * 64 + j*16 + n] = at[j][r];
}

// ---------------------------------------------------------------------------
// Chunked retention stage 2: decayed prefix scan over chunks.
//   St[bh][c] = S_c (bf16),  S_{c+1} = g^64 * S_c + AT[bh][c],  S_0 = 0
// ---------------------------------------------------------------------------
__global__ __launch_bounds__(256) void ret_scan_k(
    const float* __restrict__ AT, unsigned short* __restrict__ St)
{
  const int q = blockIdx.x, bh = blockIdx.y;
  const float lg = log2f(1.0f - exp2f(-5.0f - (float)(bh & 7)));
  const float g64 = exp2f(64.0f * lg);
  const size_t eoff = (size_t)q * 1024 + (size_t)threadIdx.x * 4;
  const float* Ab = AT + (((size_t)bh * 32) << 12) + eoff;
  unsigned short* Sb = St + (((size_t)bh * 32) << 12) + eoff;
  float4 S = make_float4(0.f, 0.f, 0.f, 0.f);
  float4 nxt = *(const float4*)Ab;
  for (int c = 0; c < 32; ++c) {
    float4 a = nxt;
    if (c < 31) nxt = *(const float4*)(Ab + ((size_t)(c + 1) << 12));
    u16x4 o;
    o[0] = f2bf(S.x); o[1] = f2bf(S.y); o[2] = f2bf(S.z); o[3] = f2bf(S.w);
    *(u16x4*)(Sb + ((size_t)c << 12)) = o;
    S.x = fmaf(g64, S.x, a.x); S.y = fmaf(g64, S.y, a.y);
    S.z = fmaf(g64, S.z, a.z); S.w = fmaf(g64, S.w, a.w);
  }
}

// ---------------------------------------------------------------------------
// Chunked retention stage 3: per (b,h,chunk) output
//   O[i] = intra(diag flash tile) + 0.125 * gamma^i * (Q @ S_c^T-layout)
// ---------------------------------------------------------------------------
__global__ __launch_bounds__(256) void ret_o_k(
    const unsigned short* __restrict__ Qb, const unsigned short* __restrict__ Kb,
    const unsigned short* __restrict__ Vb, const unsigned short* __restrict__ St,
    float* __restrict__ RET)
{
  __shared__ __align__(16) unsigned short Qs[64 * LDST];
  __shared__ __align__(16) unsigned short Ks[64 * LDST];
  __shared__ __align__(16) unsigned short Vst[64 * LDST]; // [d2][m]
  __shared__ __align__(16) unsigned short Ss[64 * LDST];  // [d2][d1]
  __shared__ __align__(16) unsigned short Ps[64 * LDST];
  const int c = blockIdx.x, h = blockIdx.y, b = blockIdx.z;
  const int bh = b * NH + h;
  const int tid = threadIdx.x;
  const int wave = tid >> 6, lane = tid & 63;
  const int n = lane & 15, quad = lane >> 4;
  const size_t base = ((size_t)b * T_SEQ + (size_t)c * 64) * DMODEL + h * DH;
  const unsigned short* Sg = St + (((size_t)bh * 32 + c) << 12);
  const float lg = log2f(1.0f - exp2f(-5.0f - (float)h));

  #pragma unroll
  for (int r = 0; r < 2; ++r) {
    int idx = r * 256 + tid;
    int i = idx >> 3, ch = idx & 7;
    *(s16x8*)&Qs[i * LDST + ch * 8] =
        *(const s16x8*)&Qb[base + (size_t)i * DMODEL + ch * 8];
    *(s16x8*)&Ks[i * LDST + ch * 8] =
        *(const s16x8*)&Kb[base + (size_t)i * DMODEL + ch * 8];
    *(s16x8*)&Ss[i * LDST + ch * 8] = *(const s16x8*)&Sg[i * 64 + ch * 8];
  }
  #pragma unroll
  for (int r = 0; r < 2; ++r) {
    int idx = r * 256 + tid;
    int m = idx & 63, ch = idx >> 6;
    s16x8 vv = *(const s16x8*)&Vb[base + (size_t)m * DMODEL + ch * 8];
    #pragma unroll
    for (int e = 0; e < 8; ++e)
      Vst[(ch * 8 + e) * LDST + m] = ((unsigned short*)&vv)[e];
  }
  __syncthreads();

  f32x4 s[4], u[4];
  #pragma unroll
  for (int j = 0; j < 4; ++j) {
    s[j] = (f32x4){0.f,0.f,0.f,0.f};
    u[j] = (f32x4){0.f,0.f,0.f,0.f};
  }
  #pragma unroll
  for (int kk = 0; kk < 2; ++kk) {
    s16x8 a = *(const s16x8*)&Qs[(wave*16 + n) * LDST + kk*32 + quad*8];
    #pragma unroll
    for (int j = 0; j < 4; ++j) {
      s16x8 bk = *(const s16x8*)&Ks[(j*16 + n) * LDST + kk*32 + quad*8];
      s[j] = __builtin_amdgcn_mfma_f32_16x16x32_bf16(a, bk, s[j], 0, 0, 0);
      s16x8 bs = *(const s16x8*)&Ss[(j*16 + n) * LDST + kk*32 + quad*8];
      u[j] = __builtin_amdgcn_mfma_f32_16x16x32_bf16(a, bs, u[j], 0, 0, 0);
    }
  }

  float rowf[4], colf[4];
  #pragma unroll
  for (int r = 0; r < 4; ++r) rowf[r] = exp2f((float)(wave*16 + quad*4 + r) * lg);
  #pragma unroll
  for (int j = 0; j < 4; ++j) colf[j] = exp2f(-(float)(j*16 + n) * lg);

  #pragma unroll
  for (int j = 0; j < 4; ++j)
    #pragma unroll
    for (int r = 0; r < 4; ++r) {
      int i = wave*16 + quad*4 + r, mcol = j*16 + n;
      float v = (mcol <= i) ? s[j][r] * 0.125f * rowf[r] * colf[j] : 0.0f;
      Ps[i * LDST + mcol] = f2bf(v);
    }
  __syncthreads();

  f32x4 acc[4];
  #pragma unroll
  for (int j = 0; j < 4; ++j) acc[j] = (f32x4){0.f,0.f,0.f,0.f};
  #pragma unroll
  for (int kk = 0; kk < 2; ++kk) {
    s16x8 a = *(const s16x8*)&Ps[(wave*16 + n) * LDST + kk*32 + quad*8];
    #pragma unroll
    for (int j = 0; j < 4; ++j) {
      s16x8 bf = *(const s16x8*)&Vst[(j*16 + n) * LDST + kk*32 + quad*8];
      acc[j] = __builtin_amdgcn_mfma_f32_16x16x32_bf16(a, bf, acc[j], 0, 0, 0);
    }
  }

  #pragma unroll
  for (int j = 0; j < 4; ++j)
    #pragma unroll
    for (int r = 0; r < 4; ++r) {
      int i = wave*16 + quad*4 + r;
      RET[((size_t)b * T_SEQ + (size_t)c * 64 + i) * DMODEL + h*DH + j*16 + n] =
          acc[j][r] + 0.125f * rowf[r] * u[j][r];
    }
}

// ---------------------------------------------------------------------------
// GroupNorm + gate: Sb = silu(G + gn(RET)*w + b), emitted as bf16
// ---------------------------------------------------------------------------
__global__ __launch_bounds__(512) void gn_gate_k(
    const float* __restrict__ RET, const float* __restrict__ Gg,
    const float* __restrict__ gw, const float* __restrict__ gb,
    unsigned short* __restrict__ S)
{
  const int row = blockIdx.x;
  const int tid = threadIdx.x;
  const float r = RET[(size_t)row * DMODEL + tid];
  float sum = r, sq = r * r;
  #pragma unroll
  for (int off = 32; off > 0; off >>= 1) {
    sum += __shfl_xor(sum, off, 64);
    sq  += __shfl_xor(sq,  off, 64);
  }
  const float mean = sum * (1.0f / 64.0f);
  float var = sq * (1.0f / 64.0f) - mean * mean;
  var = fmaxf(var, 0.0f);
  const float rstd = rsqrtf(var + 1e-5f);
  const float normed = (r - mean) * rstd * gw[tid] + gb[tid];
  const float u = Gg[(size_t)row * DMODEL + tid] + normed;
  S[(size_t)row * DMODEL + tid] = f2bf(u / (1.0f + expf(-u)));
}

// ---------------------------------------------------------------------------
extern "C" void kernel_launch(void* const* d_in, const int* in_sizes, int n_in,
                              void* d_out, int out_size, void* d_ws, size_t ws_size,
                              hipStream_t stream) {
  const float* x   = (const float*)d_in[0];
  const float* WQ  = (const float*)d_in[1];
  const float* WK  = (const float*)d_in[2];
  const float* WV  = (const float*)d_in[3];
  const float* WG  = (const float*)d_in[4];
  const float* WO  = (const float*)d_in[5];
  const float* gnw = (const float*)d_in[6];
  const float* gnb = (const float*)d_in[7];
  float* out = (float*)d_out;

  char* ws = (char*)d_ws;
  unsigned short* Xb = (unsigned short*)(ws);                 // 4 MB
  unsigned short* Qb = (unsigned short*)(ws + 4  * (1<<20));  // 4 MB
  unsigned short* Kb = (unsigned short*)(ws + 8  * (1<<20));  // 4 MB
  unsigned short* Vb = (unsigned short*)(ws + 12 * (1<<20));  // 4 MB
  float* G   = (float*)(ws + 16 * (1<<20));                   // 8 MB
  float* AT  = (float*)(ws + 24 * (1<<20));                   // 8 MB
  float* RET = AT;  // safe alias: AT fully rewritten by ret_kv_k each launch,
                    // dead after ret_scan_k, before ret_o_k writes RET
  unsigned short* Sb = (unsigned short*)(ws + 32 * (1<<20));  // 4 MB
  unsigned short* WT = (unsigned short*)(ws + 36 * (1<<20));  // 2.5 MB
  unsigned short* St = (unsigned short*)(ws + 40 * (1<<20));  // 4 MB
  (void)ws_size;

  // 0) casts / weight transposes
  cast_x_k<<<dim3(M_ROWS * DMODEL / (256 * 8)), 256, 0, stream>>>(x, Xb);
  prep_w_k<<<dim3(8, 8, 5), 256, 0, stream>>>(WQ, WK, WV, WG, WO, WT);
  // 1) fused projections (stacked N=2048): Qb,Kb,Vb bf16 + G fp32
  mfma_gemm_k<<<dim3(16, M_ROWS / 128), 256, 0, stream>>>(
      Xb, WT, Qb, Kb, Vb, G, 3);
  // 2) chunked retention: KV outer products -> scan -> outputs
  ret_kv_k<<<dim3(T_SEQ / 64, NH, 2), 256, 0, stream>>>(Kb, Vb, AT);
  ret_scan_k<<<dim3(4, 16), 256, 0, stream>>>(AT, St);
  ret_o_k<<<dim3(T_SEQ / 64, NH, 2), 256, 0, stream>>>(Qb, Kb, Vb, St, RET);
  // 3) groupnorm + silu gate -> bf16
  gn_gate_k<<<dim3(M_ROWS), 512, 0, stream>>>(RET, G, gnw, gnb, Sb);
  // 4) output projection (fp32 out)
  mfma_gemm_k<<<dim3(4, M_ROWS / 128), 256, 0, stream>>>(
      Sb, WT + 4 * DMODEL * DMODEL, out, out, out, out, 0);
}

// Round 5
// 126.524 us; speedup vs baseline: 34.0472x; 1.0147x over previous
//
#include <hip/hip_runtime.h>
#include <hip/hip_bf16.h>
#include <math.h>

#define DMODEL 512
#define T_SEQ 2048
#define NH 8
#define DH 64
#define M_ROWS 4096
#define LDST 72   // padded LDS row stride (retention kernels only)

typedef short s16x8 __attribute__((ext_vector_type(8)));
typedef float f32x4 __attribute__((ext_vector_type(4)));
typedef unsigned short u16x4 __attribute__((ext_vector_type(4)));

static __device__ __forceinline__ unsigned short f2bf(float f) {
  __hip_bfloat16 h = __float2bfloat16(f);
  return *(unsigned short*)&h;
}
static __device__ __forceinline__ float bf2f(unsigned short u) {
  union { unsigned int i; float f; } x; x.i = (unsigned int)u << 16; return x.f;
}
// async global->LDS 16B copy; LDS dest must be wave-uniform base + lane*16
static __device__ __forceinline__ void gld16(void* lds, const void* g) {
  __builtin_amdgcn_global_load_lds(
      (const __attribute__((address_space(1))) unsigned int*)g,
      (__attribute__((address_space(3))) unsigned int*)lds, 16, 0, 0);
}

// ---------------------------------------------------------------------------
// Fused prep: blocks 0..1023 cast x -> bf16; blocks 1024..1343 transpose+cast
// the 5 weight matrices: WT[z*512 + n][k] = W_z[k][n].
// ---------------------------------------------------------------------------
__global__ __launch_bounds__(256) void prep_k(
    const float* __restrict__ x, unsigned short* __restrict__ Xb,
    const float* __restrict__ W0, const float* __restrict__ W1,
    const float* __restrict__ W2, const float* __restrict__ W3,
    const float* __restrict__ W4, unsigned short* __restrict__ WT)
{
  __shared__ __align__(16) unsigned short buf[64 * LDST];
  const int bid = blockIdx.x, tid = threadIdx.x;
  if (bid < 1024) {
    const size_t i = ((size_t)bid * 256 + tid) * 8;
    float4 a = *(const float4*)&x[i];
    float4 b = *(const float4*)&x[i + 4];
    s16x8 o;
    o[0]=f2bf(a.x); o[1]=f2bf(a.y); o[2]=f2bf(a.z); o[3]=f2bf(a.w);
    o[4]=f2bf(b.x); o[5]=f2bf(b.y); o[6]=f2bf(b.z); o[7]=f2bf(b.w);
    *(s16x8*)&Xb[i] = o;
    return;
  }
  const int bid2 = bid - 1024;
  const int z = bid2 >> 6, rem = bid2 & 63;
  const int n0 = (rem & 7) * 64, k0 = (rem >> 3) * 64;
  const float* W = (z==0)?W0:(z==1)?W1:(z==2)?W2:(z==3)?W3:W4;
  #pragma unroll
  for (int r = 0; r < 4; ++r) {
    int idx = r * 256 + tid;
    int kr = idx >> 4, nc = idx & 15;
    float4 v = *(const float4*)&W[(size_t)(k0 + kr) * DMODEL + n0 + nc * 4];
    buf[(nc*4+0) * LDST + kr] = f2bf(v.x);
    buf[(nc*4+1) * LDST + kr] = f2bf(v.y);
    buf[(nc*4+2) * LDST + kr] = f2bf(v.z);
    buf[(nc*4+3) * LDST + kr] = f2bf(v.w);
  }
  __syncthreads();
  #pragma unroll
  for (int r = 0; r < 2; ++r) {
    int idx = r * 256 + tid;
    int nr = idx >> 3, c = idx & 7;
    *(s16x8*)&WT[((size_t)z * DMODEL + n0 + nr) * DMODEL + k0 + c * 8] =
        *(const s16x8*)&buf[nr * LDST + c * 8];
  }
}

// ---------------------------------------------------------------------------
// C = A(M x 512, bf16) @ BT^T, 128x128 tile, BK=64, 2x2 waves of 64x64.
// m97-style: global_load_lds width-16 into unpadded LDS with XOR chunk
// swizzle (chunk ^= row&7) -> ds_read_b128 fragments are 2-way aliased (free).
// z = stacked-N / 512 selects output; z < nbf16 stores bf16 else fp32.
// ---------------------------------------------------------------------------
__global__ __launch_bounds__(256) void mfma_gemm_k(
    const unsigned short* __restrict__ A, const unsigned short* __restrict__ BT,
    void* __restrict__ C0, void* __restrict__ C1,
    void* __restrict__ C2, void* __restrict__ C3, int nbf16)
{
  __shared__ __align__(16) unsigned short As[128 * 64];
  __shared__ __align__(16) unsigned short Bs[128 * 64];
  const int ng0 = blockIdx.x * 128;
  const int m0 = blockIdx.y * 128;
  const int z = ng0 >> 9, n0 = ng0 & 511;
  void* Cz = (z==0)?C0:(z==1)?C1:(z==2)?C2:C3;
  const int tid = threadIdx.x;
  const int wave = tid >> 6, lane = tid & 63;
  const int wm = wave >> 1, wn = wave & 1;
  const int n = lane & 15, quad = lane >> 4;

  // staging geometry: chunk idx = r*256+tid -> row = idx>>3, slot c = idx&7;
  // slot c holds global chunk (c ^ (row&7))
  int srow[4], scol[4];
  #pragma unroll
  for (int r = 0; r < 4; ++r) {
    int idx = r * 256 + tid;
    srow[r] = idx >> 3;
    scol[r] = ((idx & 7) ^ (srow[r] & 7)) * 8;
  }

  f32x4 acc[4][4];
  #pragma unroll
  for (int mi = 0; mi < 4; ++mi)
    #pragma unroll
    for (int ni = 0; ni < 4; ++ni) acc[mi][ni] = (f32x4){0.f,0.f,0.f,0.f};

  for (int k0 = 0; k0 < 512; k0 += 64) {
    #pragma unroll
    for (int r = 0; r < 4; ++r) {
      int idx = r * 256 + tid;
      gld16(&As[idx * 8], &A[(size_t)(m0 + srow[r]) * DMODEL + k0 + scol[r]]);
      gld16(&Bs[idx * 8], &BT[(size_t)(ng0 + srow[r]) * DMODEL + k0 + scol[r]]);
    }
    __syncthreads();
    #pragma unroll
    for (int kk = 0; kk < 2; ++kk) {
      s16x8 af[4], bf[4];
      #pragma unroll
      for (int mi = 0; mi < 4; ++mi) {
        int R = wm*64 + mi*16 + n, cc = (kk*4 + quad) ^ (n & 7);
        af[mi] = *(const s16x8*)&As[R * 64 + cc * 8];
      }
      #pragma unroll
      for (int ni = 0; ni < 4; ++ni) {
        int R = wn*64 + ni*16 + n, cc = (kk*4 + quad) ^ (n & 7);
        bf[ni] = *(const s16x8*)&Bs[R * 64 + cc * 8];
      }
      #pragma unroll
      for (int mi = 0; mi < 4; ++mi)
        #pragma unroll
        for (int ni = 0; ni < 4; ++ni)
          acc[mi][ni] = __builtin_amdgcn_mfma_f32_16x16x32_bf16(
              af[mi], bf[ni], acc[mi][ni], 0, 0, 0);
    }
    __syncthreads();
  }

  if (z < nbf16) {
    unsigned short* Cb = (unsigned short*)Cz;
    #pragma unroll
    for (int mi = 0; mi < 4; ++mi)
      #pragma unroll
      for (int ni = 0; ni < 4; ++ni)
        #pragma unroll
        for (int r = 0; r < 4; ++r)
          Cb[(size_t)(m0 + wm*64 + mi*16 + quad*4 + r) * DMODEL +
             n0 + wn*64 + ni*16 + n] = f2bf(acc[mi][ni][r]);
  } else {
    float* Cf = (float*)Cz;
    #pragma unroll
    for (int mi = 0; mi < 4; ++mi)
      #pragma unroll
      for (int ni = 0; ni < 4; ++ni)
        #pragma unroll
        for (int r = 0; r < 4; ++r)
          Cf[(size_t)(m0 + wm*64 + mi*16 + quad*4 + r) * DMODEL +
             n0 + wn*64 + ni*16 + n] = acc[mi][ni][r];
  }
}

// ---------------------------------------------------------------------------
// Chunked retention stage 1: AT[bh][c][d2][d1] = sum_m g^(64-m) K[m][d1] V[m][d2]
// ---------------------------------------------------------------------------
__global__ __launch_bounds__(256) void ret_kv_k(
    const unsigned short* __restrict__ Kb, const unsigned short* __restrict__ Vb,
    float* __restrict__ AT)
{
  __shared__ __align__(16) unsigned short Kts[64 * LDST]; // [d1][m], scaled
  __shared__ __align__(16) unsigned short Vts[64 * LDST]; // [d2][m]
  const int c = blockIdx.x, h = blockIdx.y, b = blockIdx.z;
  const int bh = b * NH + h;
  const int tid = threadIdx.x;
  const int wave = tid >> 6, lane = tid & 63;
  const int n = lane & 15, quad = lane >> 4;
  const size_t base = ((size_t)b * T_SEQ + (size_t)c * 64) * DMODEL + h * DH;
  const float lg = log2f(1.0f - exp2f(-5.0f - (float)h));

  #pragma unroll
  for (int r = 0; r < 2; ++r) {
    int idx = r * 256 + tid;
    int m = idx & 63, ch = idx >> 6;
    s16x8 kv = *(const s16x8*)&Kb[base + (size_t)m * DMODEL + ch * 8];
    s16x8 vv = *(const s16x8*)&Vb[base + (size_t)m * DMODEL + ch * 8];
    float sc = exp2f((float)(64 - m) * lg);
    #pragma unroll
    for (int e = 0; e < 8; ++e) {
      Kts[(ch * 8 + e) * LDST + m] = f2bf(bf2f(((unsigned short*)&kv)[e]) * sc);
      Vts[(ch * 8 + e) * LDST + m] = ((unsigned short*)&vv)[e];
    }
  }
  __syncthreads();

  f32x4 at[4];
  #pragma unroll
  for (int j = 0; j < 4; ++j) at[j] = (f32x4){0.f,0.f,0.f,0.f};
  #pragma unroll
  for (int kk = 0; kk < 2; ++kk) {
    s16x8 a = *(const s16x8*)&Vts[(wave*16 + n) * LDST + kk*32 + quad*8];
    #pragma unroll
    for (int j = 0; j < 4; ++j) {
      s16x8 bf = *(const s16x8*)&Kts[(j*16 + n) * LDST + kk*32 + quad*8];
      at[j] = __builtin_amdgcn_mfma_f32_16x16x32_bf16(a, bf, at[j], 0, 0, 0);
    }
  }
  float* Ab = AT + (((size_t)bh * 32 + c) << 12);
  #pragma unroll
  for (int j = 0; j < 4; ++j)
    #pragma unroll
    for (int r = 0; r < 4; ++r)
      Ab[(wave*16 + quad*4 + r) * 64 + j*16 + n] = at[j][r];
}

// ---------------------------------------------------------------------------
// Chunked retention stage 2: St[bh][c] = S_c (bf16); S_{c+1} = g^64 S_c + AT[c]
// ---------------------------------------------------------------------------
__global__ __launch_bounds__(256) void ret_scan_k(
    const float* __restrict__ AT, unsigned short* __restrict__ St)
{
  const int q = blockIdx.x, bh = blockIdx.y;
  const float lg = log2f(1.0f - exp2f(-5.0f - (float)(bh & 7)));
  const float g64 = exp2f(64.0f * lg);
  const size_t eoff = (size_t)q * 1024 + (size_t)threadIdx.x * 4;
  const float* Ab = AT + (((size_t)bh * 32) << 12) + eoff;
  unsigned short* Sb = St + (((size_t)bh * 32) << 12) + eoff;
  float4 S = make_float4(0.f, 0.f, 0.f, 0.f);
  float4 nxt = *(const float4*)Ab;
  for (int c = 0; c < 32; ++c) {
    float4 a = nxt;
    if (c < 31) nxt = *(const float4*)(Ab + ((size_t)(c + 1) << 12));
    u16x4 o;
    o[0] = f2bf(S.x); o[1] = f2bf(S.y); o[2] = f2bf(S.z); o[3] = f2bf(S.w);
    *(u16x4*)(Sb + ((size_t)c << 12)) = o;
    S.x = fmaf(g64, S.x, a.x); S.y = fmaf(g64, S.y, a.y);
    S.z = fmaf(g64, S.z, a.z); S.w = fmaf(g64, S.w, a.w);
  }
}

// ---------------------------------------------------------------------------
// Chunked retention stage 3: O = diag-tile flash + 0.125*g^i*(Q @ S_c)
// ---------------------------------------------------------------------------
__global__ __launch_bounds__(256) void ret_o_k(
    const unsigned short* __restrict__ Qb, const unsigned short* __restrict__ Kb,
    const unsigned short* __restrict__ Vb, const unsigned short* __restrict__ St,
    float* __restrict__ RET)
{
  __shared__ __align__(16) unsigned short Qs[64 * LDST];
  __shared__ __align__(16) unsigned short Ks[64 * LDST];
  __shared__ __align__(16) unsigned short Vst[64 * LDST]; // [d2][m]
  __shared__ __align__(16) unsigned short Ss[64 * LDST];  // [d2][d1]
  __shared__ __align__(16) unsigned short Ps[64 * LDST];
  const int c = blockIdx.x, h = blockIdx.y, b = blockIdx.z;
  const int bh = b * NH + h;
  const int tid = threadIdx.x;
  const int wave = tid >> 6, lane = tid & 63;
  const int n = lane & 15, quad = lane >> 4;
  const size_t base = ((size_t)b * T_SEQ + (size_t)c * 64) * DMODEL + h * DH;
  const unsigned short* Sg = St + (((size_t)bh * 32 + c) << 12);
  const float lg = log2f(1.0f - exp2f(-5.0f - (float)h));

  #pragma unroll
  for (int r = 0; r < 2; ++r) {
    int idx = r * 256 + tid;
    int i = idx >> 3, ch = idx & 7;
    *(s16x8*)&Qs[i * LDST + ch * 8] =
        *(const s16x8*)&Qb[base + (size_t)i * DMODEL + ch * 8];
    *(s16x8*)&Ks[i * LDST + ch * 8] =
        *(const s16x8*)&Kb[base + (size_t)i * DMODEL + ch * 8];
    *(s16x8*)&Ss[i * LDST + ch * 8] = *(const s16x8*)&Sg[i * 64 + ch * 8];
  }
  #pragma unroll
  for (int r = 0; r < 2; ++r) {
    int idx = r * 256 + tid;
    int m = idx & 63, ch = idx >> 6;
    s16x8 vv = *(const s16x8*)&Vb[base + (size_t)m * DMODEL + ch * 8];
    #pragma unroll
    for (int e = 0; e < 8; ++e)
      Vst[(ch * 8 + e) * LDST + m] = ((unsigned short*)&vv)[e];
  }
  __syncthreads();

  f32x4 s[4], u[4];
  #pragma unroll
  for (int j = 0; j < 4; ++j) {
    s[j] = (f32x4){0.f,0.f,0.f,0.f};
    u[j] = (f32x4){0.f,0.f,0.f,0.f};
  }
  #pragma unroll
  for (int kk = 0; kk < 2; ++kk) {
    s16x8 a = *(const s16x8*)&Qs[(wave*16 + n) * LDST + kk*32 + quad*8];
    #pragma unroll
    for (int j = 0; j < 4; ++j) {
      s16x8 bk = *(const s16x8*)&Ks[(j*16 + n) * LDST + kk*32 + quad*8];
      s[j] = __builtin_amdgcn_mfma_f32_16x16x32_bf16(a, bk, s[j], 0, 0, 0);
      s16x8 bs = *(const s16x8*)&Ss[(j*16 + n) * LDST + kk*32 + quad*8];
      u[j] = __builtin_amdgcn_mfma_f32_16x16x32_bf16(a, bs, u[j], 0, 0, 0);
    }
  }

  float rowf[4], colf[4];
  #pragma unroll
  for (int r = 0; r < 4; ++r) rowf[r] = exp2f((float)(wave*16 + quad*4 + r) * lg);
  #pragma unroll
  for (int j = 0; j < 4; ++j) colf[j] = exp2f(-(float)(j*16 + n) * lg);

  #pragma unroll
  for (int j = 0; j < 4; ++j)
    #pragma unroll
    for (int r = 0; r < 4; ++r) {
      int i = wave*16 + quad*4 + r, mcol = j*16 + n;
      float v = (mcol <= i) ? s[j][r] * 0.125f * rowf[r] * colf[j] : 0.0f;
      Ps[i * LDST + mcol] = f2bf(v);
    }
  __syncthreads();

  f32x4 acc[4];
  #pragma unroll
  for (int j = 0; j < 4; ++j) acc[j] = (f32x4){0.f,0.f,0.f,0.f};
  #pragma unroll
  for (int kk = 0; kk < 2; ++kk) {
    s16x8 a = *(const s16x8*)&Ps[(wave*16 + n) * LDST + kk*32 + quad*8];
    #pragma unroll
    for (int j = 0; j < 4; ++j) {
      s16x8 bf = *(const s16x8*)&Vst[(j*16 + n) * LDST + kk*32 + quad*8];
      acc[j] = __builtin_amdgcn_mfma_f32_16x16x32_bf16(a, bf, acc[j], 0, 0, 0);
    }
  }

  #pragma unroll
  for (int j = 0; j < 4; ++j)
    #pragma unroll
    for (int r = 0; r < 4; ++r) {
      int i = wave*16 + quad*4 + r;
      RET[((size_t)b * T_SEQ + (size_t)c * 64 + i) * DMODEL + h*DH + j*16 + n] =
          acc[j][r] + 0.125f * rowf[r] * u[j][r];
    }
}

// ---------------------------------------------------------------------------
// GroupNorm + gate: Sb = silu(G + gn(RET)*w + b) -> bf16 (G is bf16 now)
// ---------------------------------------------------------------------------
__global__ __launch_bounds__(512) void gn_gate_k(
    const float* __restrict__ RET, const unsigned short* __restrict__ Gg,
    const float* __restrict__ gw, const float* __restrict__ gb,
    unsigned short* __restrict__ S)
{
  const int row = blockIdx.x;
  const int tid = threadIdx.x;
  const float r = RET[(size_t)row * DMODEL + tid];
  float sum = r, sq = r * r;
  #pragma unroll
  for (int off = 32; off > 0; off >>= 1) {
    sum += __shfl_xor(sum, off, 64);
    sq  += __shfl_xor(sq,  off, 64);
  }
  const float mean = sum * (1.0f / 64.0f);
  float var = sq * (1.0f / 64.0f) - mean * mean;
  var = fmaxf(var, 0.0f);
  const float rstd = rsqrtf(var + 1e-5f);
  const float normed = (r - mean) * rstd * gw[tid] + gb[tid];
  const float u = bf2f(Gg[(size_t)row * DMODEL + tid]) + normed;
  S[(size_t)row * DMODEL + tid] = f2bf(u / (1.0f + expf(-u)));
}

// ---------------------------------------------------------------------------
extern "C" void kernel_launch(void* const* d_in, const int* in_sizes, int n_in,
                              void* d_out, int out_size, void* d_ws, size_t ws_size,
                              hipStream_t stream) {
  const float* x   = (const float*)d_in[0];
  const float* WQ  = (const float*)d_in[1];
  const float* WK  = (const float*)d_in[2];
  const float* WV  = (const float*)d_in[3];
  const float* WG  = (const float*)d_in[4];
  const float* WO  = (const float*)d_in[5];
  const float* gnw = (const float*)d_in[6];
  const float* gnb = (const float*)d_in[7];
  float* out = (float*)d_out;

  char* ws = (char*)d_ws;
  unsigned short* Xb = (unsigned short*)(ws);                 // 4 MB
  unsigned short* Qb = (unsigned short*)(ws + 4  * (1<<20));  // 4 MB
  unsigned short* Kb = (unsigned short*)(ws + 8  * (1<<20));  // 4 MB
  unsigned short* Vb = (unsigned short*)(ws + 12 * (1<<20));  // 4 MB
  unsigned short* G  = (unsigned short*)(ws + 16 * (1<<20));  // 4 MB (bf16)
  float* AT  = (float*)(ws + 24 * (1<<20));                   // 8 MB
  float* RET = AT;  // safe alias: AT fully rewritten before reads each launch
  unsigned short* Sb = (unsigned short*)(ws + 32 * (1<<20));  // 4 MB
  unsigned short* WT = (unsigned short*)(ws + 36 * (1<<20));  // 2.5 MB
  unsigned short* St = (unsigned short*)(ws + 40 * (1<<20));  // 4 MB
  (void)ws_size;

  // 0) fused cast-x + weight transposes
  prep_k<<<dim3(1024 + 320), 256, 0, stream>>>(x, Xb, WQ, WK, WV, WG, WO, WT);
  // 1) fused projections (stacked N=2048): Qb,Kb,Vb,G all bf16
  mfma_gemm_k<<<dim3(16, M_ROWS / 128), 256, 0, stream>>>(
      Xb, WT, Qb, Kb, Vb, G, 4);
  // 2) chunked retention: KV outer products -> scan -> outputs
  ret_kv_k<<<dim3(T_SEQ / 64, NH, 2), 256, 0, stream>>>(Kb, Vb, AT);
  ret_scan_k<<<dim3(4, 16), 256, 0, stream>>>(AT, St);
  ret_o_k<<<dim3(T_SEQ / 64, NH, 2), 256, 0, stream>>>(Qb, Kb, Vb, St, RET);
  // 3) groupnorm + silu gate -> bf16
  gn_gate_k<<<dim3(M_ROWS), 512, 0, stream>>>(RET, G, gnw, gnb, Sb);
  // 4) output projection (fp32 out)
  mfma_gemm_k<<<dim3(4, M_ROWS / 128), 256, 0, stream>>>(
      Sb, WT + 4 * DMODEL * DMODEL, out, out, out, out, 0);
}